// Round 3
// baseline (1563.027 us; speedup 1.0000x reference)
//
#include <hip/hip_runtime.h>
#include <cstdint>
#include <cstddef>

typedef __bf16 bf16x8 __attribute__((ext_vector_type(8)));
typedef float  f32x4  __attribute__((ext_vector_type(4)));

#define MFMA16(a,b,c) __builtin_amdgcn_mfma_f32_16x16x32_bf16((a),(b),(c),0,0,0)

// Problem constants: B=256, T=512, D=H=128, 3H=384.
// x / out row stride per batch: T*128 = 65536 elems.

// ---------------------------------------------------------------------------
// prep_frags: MFMA B-operand frag-ordered bf16 weights.
// Frag layout (16x16x32): B[k][n], n = lane&15, k = kt*32 + (lane>>4)*8 + j
// Elem offset = ((ct*4+kt)*64 + lane)*8 + j, ct 0..23 (z:0-7, r:8-15, h:16-23).
// Outputs (each 49152 bf16): [0]=W0 [1]=U0 [2]=W1 [3]=U1
// ---------------------------------------------------------------------------
__global__ void prep_frags(const float* __restrict__ W0, const float* __restrict__ U0,
                           const float* __restrict__ W1, const float* __restrict__ U1,
                           __bf16* __restrict__ frags)
{
    int id = blockIdx.x * 512 + threadIdx.x;      // 0..24575
    int mat = id / 6144;                          // 0..3 : W0,U0,W1,U1
    int r   = id % 6144;                          // (ct*4+kt)*64 + lane
    int lane = r & 63;
    int ctkt = r >> 6;
    int kt = ctkt & 3;
    int ct = ctkt >> 2;
    const float* src = (mat == 0) ? W0 : (mat == 1) ? U0 : (mat == 2) ? W1 : U1;
    int n  = ct * 16 + (lane & 15);
    int k0 = kt * 32 + (lane >> 4) * 8;
    __bf16* dst = frags + (size_t)mat * 49152 + (size_t)r * 8;
#pragma unroll
    for (int j = 0; j < 8; j++)
        dst[j] = (__bf16)src[(size_t)(k0 + j) * 384 + n];
}

// ---------------------------------------------------------------------------
// gru_fused: one GRU layer, input projection fused into the scan.
// 16 blocks x 256 threads (4 waves, 1 wave/SIMD, full VGPR budget).
// Block: 16 batch rows, T=512 steps. Wave w owns hidden col-tiles {w, w+4}
// for all 3 gates (B-frag col-tile ct = 8*g + w + 4*i).
// xp = (xH + xL) @ Wbf16  (x exact in hi+lo bf16; only W quantized).
// rec = hbf16 @ Ubf16.
// LDS double-buffered (xH, xL, h); ONE barrier per step; x prefetch 2 ahead.
// xin may alias hout (in-place layer 1): reads of x[b,t+2] precede writes of
// out[b,t]; blocks own disjoint batch rows. No __restrict__ on xin/hout.
// ---------------------------------------------------------------------------
__global__ __launch_bounds__(256, 1) void gru_fused(
    const float* xin, const __bf16* __restrict__ Uf, const __bf16* __restrict__ Wf,
    const float* __restrict__ bias, float* hout)
{
    __shared__ __align__(16) __bf16 xbh[2][16 * 136];
    __shared__ __align__(16) __bf16 xbl[2][16 * 136];
    __shared__ __align__(16) __bf16 hbuf[2][16 * 136];

    const int tid = threadIdx.x;
    const int wave = tid >> 6, lane = tid & 63;
    const int l15 = lane & 15, quad = lane >> 4;
    const int B0 = blockIdx.x * 16;

    // persistent B-frags: (W + U) x 3 gates x 2 tiles x 4 kt = 48 frags (192 VGPR)
    bf16x8 wf[3][2][4], uf[3][2][4];
#pragma unroll
    for (int g = 0; g < 3; g++)
#pragma unroll
        for (int i = 0; i < 2; i++) {
            int ct = 8 * g + wave + 4 * i;
#pragma unroll
            for (int kt = 0; kt < 4; kt++) {
                size_t off = (size_t)((ct * 4 + kt) * 64 + lane) * 8;
                wf[g][i][kt] = *(const bf16x8*)(Wf + off);
                uf[g][i][kt] = *(const bf16x8*)(Uf + off);
            }
        }

    const int j0 = wave * 16 + l15;            // hidden cols owned by this lane
    const int jj[2] = { j0, j0 + 64 };
    float bz[2], br[2], bih[2], brh[2];
#pragma unroll
    for (int i = 0; i < 2; i++) {
        bz[i]  = bias[jj[i]]       + bias[384 + jj[i]];
        br[i]  = bias[128 + jj[i]] + bias[512 + jj[i]];
        bih[i] = bias[256 + jj[i]];
        brh[i] = bias[640 + jj[i]];
    }

    // staging map: 256 threads cover 16 rows x 128 cols (8 floats each)
    const int srow = tid >> 4;
    const int c8   = tid & 15;
    const float* px = xin + (size_t)(B0 + srow) * 65536 + c8 * 8;
    const int sidx = srow * 136 + c8 * 8;

    const size_t obase = (size_t)(B0 + quad * 4) * 65536;

    // ---- prologue: stage x_0, preload x_1, zero h ----
    float4 vc0 = *(const float4*)(px);
    float4 vc1 = *(const float4*)(px + 4);
    {
        bf16x8 hv, lv;
        float f[8] = {vc0.x, vc0.y, vc0.z, vc0.w, vc1.x, vc1.y, vc1.z, vc1.w};
#pragma unroll
        for (int k = 0; k < 8; k++) {
            __bf16 h = (__bf16)f[k];
            hv[k] = h;
            lv[k] = (__bf16)(f[k] - (float)h);
        }
        *(bf16x8*)&xbh[0][sidx] = hv;
        *(bf16x8*)&xbl[0][sidx] = lv;
    }
    vc0 = *(const float4*)(px + 128);
    vc1 = *(const float4*)(px + 132);
#pragma unroll
    for (int i = tid; i < 272; i += 256)
        ((uint4*)&hbuf[0][0])[i] = make_uint4(0, 0, 0, 0);
    __syncthreads();

    float hold[2][4] = {{0,0,0,0},{0,0,0,0}};
    const int abase = l15 * 136 + quad * 8;

    for (int t = 0; t < 512; t++) {
        const int cur = t & 1, nxt = cur ^ 1;
        const int t2 = (t < 510) ? (t + 2) : 511;       // 2-step-ahead prefetch
        float4 vn0 = *(const float4*)(px + (size_t)t2 * 128);
        float4 vn1 = *(const float4*)(px + (size_t)t2 * 128 + 4);

        // A-frags from LDS
        bf16x8 xH[4], xL[4], hA[4];
#pragma unroll
        for (int kt = 0; kt < 4; kt++) {
            xH[kt] = *(const bf16x8*)&xbh[cur][abase + kt * 32];
            xL[kt] = *(const bf16x8*)&xbl[cur][abase + kt * 32];
            hA[kt] = *(const bf16x8*)&hbuf[cur][abase + kt * 32];
        }

        f32x4 xa[3][2], ha[3][2];
#pragma unroll
        for (int g = 0; g < 3; g++)
#pragma unroll
            for (int i = 0; i < 2; i++) { xa[g][i] = (f32x4){0,0,0,0}; ha[g][i] = (f32x4){0,0,0,0}; }

#pragma unroll
        for (int kt = 0; kt < 4; kt++) {
#pragma unroll
            for (int g = 0; g < 3; g++)
#pragma unroll
                for (int i = 0; i < 2; i++)
                    xa[g][i] = MFMA16(xH[kt], wf[g][i][kt], xa[g][i]);
#pragma unroll
            for (int g = 0; g < 3; g++)
#pragma unroll
                for (int i = 0; i < 2; i++)
                    ha[g][i] = MFMA16(hA[kt], uf[g][i][kt], ha[g][i]);
#pragma unroll
            for (int g = 0; g < 3; g++)
#pragma unroll
                for (int i = 0; i < 2; i++)
                    xa[g][i] = MFMA16(xL[kt], wf[g][i][kt], xa[g][i]);
        }

        float hnew[2][4];
#pragma unroll
        for (int i = 0; i < 2; i++)
#pragma unroll
            for (int r = 0; r < 4; r++) {
                float zp = xa[0][i][r] + ha[0][i][r] + bz[i];
                float rp = xa[1][i][r] + ha[1][i][r] + br[i];
                float z  = __builtin_amdgcn_rcpf(1.f + __expf(-zp));
                float rg = __builtin_amdgcn_rcpf(1.f + __expf(-rp));
                float hp = (xa[2][i][r] + bih[i]) + rg * (ha[2][i][r] + brh[i]);
                float e2 = __expf(2.f * hp);
                float th = 1.f - 2.f * __builtin_amdgcn_rcpf(e2 + 1.f);
                hnew[i][r] = th + z * (hold[i][r] - th);
                hold[i][r] = hnew[i][r];
            }

        // stage x_{t+1} (held in vc from previous iteration's prefetch)
        {
            bf16x8 hv, lv;
            float f[8] = {vc0.x, vc0.y, vc0.z, vc0.w, vc1.x, vc1.y, vc1.z, vc1.w};
#pragma unroll
            for (int k = 0; k < 8; k++) {
                __bf16 h = (__bf16)f[k];
                hv[k] = h;
                lv[k] = (__bf16)(f[k] - (float)h);
            }
            *(bf16x8*)&xbh[nxt][sidx] = hv;
            *(bf16x8*)&xbl[nxt][sidx] = lv;
        }
        // h_t -> LDS (next buffer)
#pragma unroll
        for (int i = 0; i < 2; i++)
#pragma unroll
            for (int r = 0; r < 4; r++)
                hbuf[nxt][(quad * 4 + r) * 136 + jj[i]] = (__bf16)hnew[i][r];

        __syncthreads();   // single barrier: t+1 buffers visible

        // h_t -> global (drains during next step)
#pragma unroll
        for (int i = 0; i < 2; i++)
#pragma unroll
            for (int r = 0; r < 4; r++)
                hout[obase + (size_t)r * 65536 + (size_t)t * 128 + jj[i]] = hnew[i][r];

        vc0 = vn0; vc1 = vn1;
    }
}

// ---------------------------------------------------------------------------
extern "C" void kernel_launch(void* const* d_in, const int* in_sizes, int n_in,
                              void* d_out, int out_size, void* d_ws, size_t ws_size,
                              hipStream_t stream)
{
    const float* x  = (const float*)d_in[0];
    const float* W0 = (const float*)d_in[1];
    const float* U0 = (const float*)d_in[2];
    const float* b0 = (const float*)d_in[3];
    const float* W1 = (const float*)d_in[4];
    const float* U1 = (const float*)d_in[5];
    const float* b1 = (const float*)d_in[6];
    float* out = (float*)d_out;

    char* ws = (char*)d_ws;
    __bf16* frags = (__bf16*)ws;                 // 4 * 49152 bf16 = 393,216 B
    const __bf16* W0f = frags;
    const __bf16* U0f = frags + 49152;
    const __bf16* W1f = frags + 2 * 49152;
    const __bf16* U1f = frags + 3 * 49152;

    // h0 inter-layer buffer: ws if it fits, else in-place through d_out
    float* h0;
    const size_t need = 393216 + 67108864;
    if (ws_size >= need) h0 = (float*)(ws + 393216);
    else                 h0 = out;

    prep_frags<<<48, 512, 0, stream>>>(W0, U0, W1, U1, frags);
    gru_fused<<<16, 256, 0, stream>>>(x,  U0f, W0f, b0, h0);
    gru_fused<<<16, 256, 0, stream>>>(h0, U1f, W1f, b1, out);
}

// Round 4
// 1064.637 us; speedup vs baseline: 1.4681x; 1.4681x over previous
//
#include <hip/hip_runtime.h>
#include <cstdint>
#include <cstddef>

typedef __bf16 bf16x8 __attribute__((ext_vector_type(8)));
typedef __bf16 bf16x4 __attribute__((ext_vector_type(4)));
typedef float  f32x4  __attribute__((ext_vector_type(4)));

#define MFMA16(a,b,c) __builtin_amdgcn_mfma_f32_16x16x32_bf16((a),(b),(c),0,0,0)

// Problem: B=256, T=512, D=H=128, 3H=384. x/out batch stride = 65536 elems.
// Per layer: fused scan computing A=[x_t | h_{t-1}] (K=256, bf16) against
// stacked B=[W;U] frags. Gates z,r use merged K=256 accumulators; gate h
// keeps xh (kt 0..3) and rec_h (kt 4..7) in separate accumulators because
// reset_after multiplies r into the recurrent part only.

// ---------------------------------------------------------------------------
// prep_frags: stacked-weight B-frags, K=256 ([W(128) ; U(128)]).
// Frag layout (16x16x32): B[k][n], n = lane&15, k = kt*32 + (lane>>4)*8 + j.
// Elem offset = ((ct*8+kt)*64 + lane)*8 + j, ct 0..23 (z:0-7,r:8-15,h:16-23),
// kt 0..7 (kt<4 -> W rows k, kt>=4 -> U rows k-128). Per layer: 98304 bf16.
// ---------------------------------------------------------------------------
__global__ void prep_frags(const float* __restrict__ W0, const float* __restrict__ U0,
                           const float* __restrict__ W1, const float* __restrict__ U1,
                           __bf16* __restrict__ frags)
{
    int id = blockIdx.x * 512 + threadIdx.x;      // 0..24575
    int layer = id / 12288;
    int r     = id % 12288;                       // (ct*8+kt)*64 + lane
    int lane = r & 63;
    int ctkt = r >> 6;                            // 0..191
    int kt = ctkt & 7;
    int ct = ctkt >> 3;
    const float* Wsrc = layer ? W1 : W0;
    const float* Usrc = layer ? U1 : U0;
    int n  = ct * 16 + (lane & 15);
    int k0 = kt * 32 + (lane >> 4) * 8;           // 0..248, never straddles 128
    const float* src = (k0 < 128) ? (Wsrc + (size_t)k0 * 384)
                                  : (Usrc + (size_t)(k0 - 128) * 384);
    __bf16* dst = frags + (size_t)layer * 98304 + (size_t)r * 8;
#pragma unroll
    for (int j = 0; j < 8; j++)
        dst[j] = (__bf16)src[(size_t)j * 384 + n];
}

// ---------------------------------------------------------------------------
// gru_fused: one GRU layer. 16 blocks x 512 threads (8 waves, 2/SIMD).
// Block: 16 batch rows, T=512 steps. Wave w owns hidden cols j=16w+l15 for
// all 3 gates (B col-tile ct = 8g + w). A = [x_t | h_{t-1}] bf16, K=256,
// LDS row stride 264 elems; double-buffered; ONE barrier per step.
// Accumulators: acc[0]=z (K=256), acc[1]=r (K=256), acc[2]=xh (kt 0..3),
// acc[3]=rec_h (kt 4..7).
// xin may alias hout (in-place layer 1): reads stay >= 2 steps ahead of
// writes; blocks own disjoint batch rows. No __restrict__ on xin/hout.
// ---------------------------------------------------------------------------
__global__ __launch_bounds__(512, 2) void gru_fused(
    const float* xin, const __bf16* __restrict__ Bf,
    const float* __restrict__ bias, float* hout)
{
    __shared__ __align__(16) __bf16 ab[2][16 * 264];

    const int tid = threadIdx.x;
    const int wave = tid >> 6, lane = tid & 63;
    const int l15 = lane & 15, quad = lane >> 4;
    const int B0 = blockIdx.x * 16;

    // persistent stacked B-frags: 3 gates x 8 kt = 24 frags (96 VGPR)
    bf16x8 bf[3][8];
#pragma unroll
    for (int g = 0; g < 3; g++) {
        int ct = 8 * g + wave;
#pragma unroll
        for (int kt = 0; kt < 8; kt++)
            bf[g][kt] = *(const bf16x8*)(Bf + (size_t)((ct * 8 + kt) * 64 + lane) * 8);
    }

    const int j = wave * 16 + l15;                 // hidden col owned by lane
    const float bz  = bias[j]       + bias[384 + j];
    const float br  = bias[128 + j] + bias[512 + j];
    const float bih = bias[256 + j];
    const float brh = bias[640 + j];

    // staging map: 512 threads cover 16 rows x 128 cols (4 floats each)
    const int srow = tid >> 5;
    const int c4   = (tid & 31) * 4;
    const float* px = xin + (size_t)(B0 + srow) * 65536 + c4;
    const int sidx = srow * 264 + c4;              // x-part cols 0..127

    const size_t obase = (size_t)(B0 + quad * 4) * 65536 + j;

    // ---- prologue: stage x_0, zero h-part, preload x_1 ----
    float4 vc = *(const float4*)px;
    {
        bf16x4 hv;
        hv.x = (__bf16)vc.x; hv.y = (__bf16)vc.y;
        hv.z = (__bf16)vc.z; hv.w = (__bf16)vc.w;
        *(bf16x4*)&ab[0][sidx] = hv;
    }
    if (tid < 256) {
        int row = tid >> 4, seg = tid & 15;
        *(uint4*)&ab[0][row * 264 + 128 + seg * 8] = make_uint4(0, 0, 0, 0);
    }
    __syncthreads();
    vc = *(const float4*)(px + 128);               // x_1

    float hold[4] = {0.f, 0.f, 0.f, 0.f};
    const int abase = l15 * 264 + quad * 8;

    for (int t = 0; t < 512; t++) {
        const int cur = t & 1, nxt = cur ^ 1;
        const int t2 = (t < 510) ? (t + 2) : 511;  // prefetch 2 ahead
        float4 vn = *(const float4*)(px + (size_t)t2 * 128);

        // A-frags: 8 K-slabs (x: kt 0..3, h: kt 4..7)
        bf16x8 A[8];
#pragma unroll
        for (int kt = 0; kt < 8; kt++)
            A[kt] = *(const bf16x8*)&ab[cur][abase + kt * 32];

        f32x4 acc[4] = {{0,0,0,0},{0,0,0,0},{0,0,0,0},{0,0,0,0}};
#pragma unroll
        for (int kt = 0; kt < 8; kt++) {
            acc[0] = MFMA16(A[kt], bf[0][kt], acc[0]);          // z (merged)
            acc[1] = MFMA16(A[kt], bf[1][kt], acc[1]);          // r (merged)
            acc[(kt < 4) ? 2 : 3] = MFMA16(A[kt], bf[2][kt], acc[(kt < 4) ? 2 : 3]);
        }

        float hnew[4];
#pragma unroll
        for (int r = 0; r < 4; r++) {
            float zp = acc[0][r] + bz;
            float rp = acc[1][r] + br;
            float z  = __builtin_amdgcn_rcpf(1.f + __expf(-zp));
            float rg = __builtin_amdgcn_rcpf(1.f + __expf(-rp));
            float hp = (acc[2][r] + bih) + rg * (acc[3][r] + brh);
            float e2 = __expf(2.f * hp);
            float th = 1.f - 2.f * __builtin_amdgcn_rcpf(e2 + 1.f);
            hnew[r] = th + z * (hold[r] - th);
            hold[r] = hnew[r];
        }

        // stage x_{t+1} (vc holds it from last iteration's prefetch)
        {
            bf16x4 hv;
            hv.x = (__bf16)vc.x; hv.y = (__bf16)vc.y;
            hv.z = (__bf16)vc.z; hv.w = (__bf16)vc.w;
            *(bf16x4*)&ab[nxt][sidx] = hv;
        }
        // h_t -> LDS h-part (cols 128..255)
#pragma unroll
        for (int r = 0; r < 4; r++)
            ab[nxt][(quad * 4 + r) * 264 + 128 + j] = (__bf16)hnew[r];

        __syncthreads();   // single barrier: t+1 A-buffer visible

        // h_t -> global (drains during next step's compute)
#pragma unroll
        for (int r = 0; r < 4; r++)
            hout[obase + (size_t)r * 65536 + (size_t)t * 128] = hnew[r];

        vc = vn;
    }
}

// ---------------------------------------------------------------------------
extern "C" void kernel_launch(void* const* d_in, const int* in_sizes, int n_in,
                              void* d_out, int out_size, void* d_ws, size_t ws_size,
                              hipStream_t stream)
{
    const float* x  = (const float*)d_in[0];
    const float* W0 = (const float*)d_in[1];
    const float* U0 = (const float*)d_in[2];
    const float* b0 = (const float*)d_in[3];
    const float* W1 = (const float*)d_in[4];
    const float* U1 = (const float*)d_in[5];
    const float* b1 = (const float*)d_in[6];
    float* out = (float*)d_out;

    char* ws = (char*)d_ws;
    __bf16* frags = (__bf16*)ws;                 // 2 * 98304 bf16 = 393,216 B
    const __bf16* B0f = frags;
    const __bf16* B1f = frags + 98304;

    // h0 inter-layer buffer: ws if it fits, else in-place through d_out
    float* h0;
    const size_t need = 393216 + 67108864;
    if (ws_size >= need) h0 = (float*)(ws + 393216);
    else                 h0 = out;

    prep_frags<<<48, 512, 0, stream>>>(W0, U0, W1, U1, frags);
    gru_fused<<<16, 512, 0, stream>>>(x,  B0f, b0, h0);
    gru_fused<<<16, 512, 0, stream>>>(h0, B1f, b1, out);
}

// Round 5
// 846.374 us; speedup vs baseline: 1.8467x; 1.2579x over previous
//
#include <hip/hip_runtime.h>
#include <cstdint>
#include <cstddef>

typedef __bf16 bf16x8 __attribute__((ext_vector_type(8)));
typedef __bf16 bf16x4 __attribute__((ext_vector_type(4)));
typedef float  f32x4  __attribute__((ext_vector_type(4)));

#define MFMA16(a,b,c) __builtin_amdgcn_mfma_f32_16x16x32_bf16((a),(b),(c),0,0,0)

// Problem: B=256, T=512, D=H=128, 3H=384. x/out batch stride = 65536 elems.
// One 32-block kernel: blocks 0..15 = layer 0 (producer), 16..31 = layer 1
// (consumer, lagged ~3 steps). h0 crosses XCDs via nt stores/loads (bypass
// non-coherent L2s) + per-pair agent-scope progress flags.

// ---------------------------------------------------------------------------
// prep_frags: stacked-weight B-frags, K=256 ([W(128) ; U(128)]), + flag init.
// Frag layout (16x16x32): B[k][n], n = lane&15, k = kt*32 + (lane>>4)*8 + j.
// Elem offset = ((ct*8+kt)*64 + lane)*8 + j, ct 0..23 (z:0-7,r:8-15,h:16-23),
// kt 0..7 (kt<4 -> W rows k, kt>=4 -> U rows k-128). Per layer: 98304 bf16.
// ---------------------------------------------------------------------------
__global__ void prep_frags(const float* __restrict__ W0, const float* __restrict__ U0,
                           const float* __restrict__ W1, const float* __restrict__ U1,
                           __bf16* __restrict__ frags, int* __restrict__ flags)
{
    if (blockIdx.x == 0 && threadIdx.x < 16) flags[threadIdx.x] = 0;
    int id = blockIdx.x * 512 + threadIdx.x;      // 0..24575
    int layer = id / 12288;
    int r     = id % 12288;                       // (ct*8+kt)*64 + lane
    int lane = r & 63;
    int ctkt = r >> 6;                            // 0..191
    int kt = ctkt & 7;
    int ct = ctkt >> 3;
    const float* Wsrc = layer ? W1 : W0;
    const float* Usrc = layer ? U1 : U0;
    int n  = ct * 16 + (lane & 15);
    int k0 = kt * 32 + (lane >> 4) * 8;           // never straddles 128
    const float* src = (k0 < 128) ? (Wsrc + (size_t)k0 * 384)
                                  : (Usrc + (size_t)(k0 - 128) * 384);
    __bf16* dst = frags + (size_t)layer * 98304 + (size_t)r * 8;
#pragma unroll
    for (int j = 0; j < 8; j++)
        dst[j] = (__bf16)src[(size_t)j * 384 + n];
}

// ---------------------------------------------------------------------------
// gru_pipe: both GRU layers, pipelined across block pairs.
// Per block: 16 batch rows, 512 threads (8 waves, 2/SIMD). Wave w owns hidden
// col j=16w+l15 for all gates. A=[x_t | h_{t-1}] bf16 K=256, LDS stride 264,
// double-buffered, ONE barrier/step. acc: z(K256), r(K256), xh(kt0-3),
// rec_h(kt4-7) — reset_after multiplies r into recurrent part only.
// Flag F for pair p means: h0 steps 0..F-1 are globally visible (nt-stored,
// drained by the barrier preceding the publish).
// h0 may alias out (small-ws fallback): consumer reads slot t+2 strictly
// before overwriting slot t. No __restrict__ on x/h0/out.
// ---------------------------------------------------------------------------
__global__ __launch_bounds__(512, 2) void gru_pipe(
    const float* x, const __bf16* __restrict__ frags,
    const float* __restrict__ b0, const float* __restrict__ b1,
    float* h0, float* out, int* flags)
{
    __shared__ __align__(16) __bf16 ab[2][16 * 264];

    const int tid = threadIdx.x;
    const int wave = tid >> 6, lane = tid & 63;
    const int l15 = lane & 15, quad = lane >> 4;
    const int pair  = blockIdx.x & 15;
    const int layer = blockIdx.x >> 4;
    const int B0 = pair * 16;

    const __bf16* Bf  = frags + (size_t)layer * 98304;
    const float* bias = layer ? b1 : b0;
    const float* xin  = layer ? h0 : x;
    float*       hout = layer ? out : h0;

    // persistent stacked B-frags: 3 gates x 8 kt = 24 frags
    bf16x8 bfr[3][8];
#pragma unroll
    for (int g = 0; g < 3; g++) {
        int ct = 8 * g + wave;
#pragma unroll
        for (int kt = 0; kt < 8; kt++)
            bfr[g][kt] = *(const bf16x8*)(Bf + (size_t)((ct * 8 + kt) * 64 + lane) * 8);
    }

    const int j = wave * 16 + l15;
    const float bz  = bias[j]       + bias[384 + j];
    const float br  = bias[128 + j] + bias[512 + j];
    const float bih = bias[256 + j];
    const float brh = bias[640 + j];

    // staging map: 512 threads cover 16 rows x 128 cols (4 floats each)
    const int srow = tid >> 5;
    const int c4   = (tid & 31) * 4;
    const float* px = xin + (size_t)(B0 + srow) * 65536 + c4;
    const int sidx = srow * 264 + c4;

    const size_t obase = (size_t)(B0 + quad * 4) * 65536 + j;

    int known = 0;
    if (layer) {
        while (known < 2)
            known = __hip_atomic_load(flags + pair, __ATOMIC_RELAXED,
                                      __HIP_MEMORY_SCOPE_AGENT);
    }

    // ---- prologue: stage x_0 (or h0_0), zero h-part, preload step 1 ----
    f32x4 vc = layer ? __builtin_nontemporal_load((const f32x4*)px)
                     : *(const f32x4*)px;
    {
        bf16x4 hv;
        hv.x = (__bf16)vc[0]; hv.y = (__bf16)vc[1];
        hv.z = (__bf16)vc[2]; hv.w = (__bf16)vc[3];
        *(bf16x4*)&ab[0][sidx] = hv;
    }
    if (tid < 256) {
        int row = tid >> 4, seg = tid & 15;
        *(uint4*)&ab[0][row * 264 + 128 + seg * 8] = make_uint4(0, 0, 0, 0);
    }
    __syncthreads();
    vc = layer ? __builtin_nontemporal_load((const f32x4*)(px + 128))
               : *(const f32x4*)(px + 128);

    float hold[4] = {0.f, 0.f, 0.f, 0.f};
    const int abase = l15 * 264 + quad * 8;

    for (int t = 0; t < 512; t++) {
        const int cur = t & 1, nxt = cur ^ 1;

        if (layer) {                                // gate the t+2 prefetch
            int need = t + 3; if (need > 512) need = 512;
            while (known < need)
                known = __hip_atomic_load(flags + pair, __ATOMIC_RELAXED,
                                          __HIP_MEMORY_SCOPE_AGENT);
        }
        const int t2 = (t < 510) ? (t + 2) : 511;
        f32x4 vn = layer
            ? __builtin_nontemporal_load((const f32x4*)(px + (size_t)t2 * 128))
            : *(const f32x4*)(px + (size_t)t2 * 128);

        // A-frags: 8 K-slabs (x: kt 0..3, h: kt 4..7)
        bf16x8 A[8];
#pragma unroll
        for (int kt = 0; kt < 8; kt++)
            A[kt] = *(const bf16x8*)&ab[cur][abase + kt * 32];

        f32x4 acc[4] = {{0,0,0,0},{0,0,0,0},{0,0,0,0},{0,0,0,0}};
#pragma unroll
        for (int kt = 0; kt < 8; kt++) {
            acc[0] = MFMA16(A[kt], bfr[0][kt], acc[0]);          // z (merged)
            acc[1] = MFMA16(A[kt], bfr[1][kt], acc[1]);          // r (merged)
            acc[(kt < 4) ? 2 : 3] = MFMA16(A[kt], bfr[2][kt], acc[(kt < 4) ? 2 : 3]);
        }

        float hnew[4];
#pragma unroll
        for (int r = 0; r < 4; r++) {
            float zp = acc[0][r] + bz;
            float rp = acc[1][r] + br;
            float z  = __builtin_amdgcn_rcpf(1.f + __expf(-zp));
            float rg = __builtin_amdgcn_rcpf(1.f + __expf(-rp));
            float hp = (acc[2][r] + bih) + rg * (acc[3][r] + brh);
            float e2 = __expf(2.f * hp);
            float th = 1.f - 2.f * __builtin_amdgcn_rcpf(e2 + 1.f);
            hnew[r] = th + z * (hold[r] - th);
            hold[r] = hnew[r];
        }

        // stage step t+1 input (vc from previous prefetch)
        {
            bf16x4 hv;
            hv.x = (__bf16)vc[0]; hv.y = (__bf16)vc[1];
            hv.z = (__bf16)vc[2]; hv.w = (__bf16)vc[3];
            *(bf16x4*)&ab[nxt][sidx] = hv;
        }
        // h_t -> LDS h-part (cols 128..255)
#pragma unroll
        for (int r = 0; r < 4; r++)
            ab[nxt][(quad * 4 + r) * 264 + 128 + j] = (__bf16)hnew[r];

        __syncthreads();   // drains step t-1 h0 nt-stores (and LDS writes)

        if (layer == 0 && tid == 0)
            __hip_atomic_store(flags + pair, t, __ATOMIC_RELAXED,
                               __HIP_MEMORY_SCOPE_AGENT);   // h0[0..t-1] visible

        // h_t -> global (drains during next step)
        if (layer == 0) {
#pragma unroll
            for (int r = 0; r < 4; r++)
                __builtin_nontemporal_store(hnew[r],
                    hout + obase + (size_t)r * 65536 + (size_t)t * 128);
        } else {
#pragma unroll
            for (int r = 0; r < 4; r++)
                hout[obase + (size_t)r * 65536 + (size_t)t * 128] = hnew[r];
        }

        vc = vn;
    }

    __syncthreads();       // drain final h0 stores
    if (layer == 0 && tid == 0)
        __hip_atomic_store(flags + pair, 512, __ATOMIC_RELAXED,
                           __HIP_MEMORY_SCOPE_AGENT);
}

// ---------------------------------------------------------------------------
extern "C" void kernel_launch(void* const* d_in, const int* in_sizes, int n_in,
                              void* d_out, int out_size, void* d_ws, size_t ws_size,
                              hipStream_t stream)
{
    const float* x  = (const float*)d_in[0];
    const float* W0 = (const float*)d_in[1];
    const float* U0 = (const float*)d_in[2];
    const float* b0 = (const float*)d_in[3];
    const float* W1 = (const float*)d_in[4];
    const float* U1 = (const float*)d_in[5];
    const float* b1 = (const float*)d_in[6];
    float* out = (float*)d_out;

    char* ws = (char*)d_ws;
    __bf16* frags = (__bf16*)ws;                 // 2 * 98304 bf16 = 393,216 B
    int*    flags = (int*)(ws + 393216);         // 16 * 4 B
    // h0 at ws + 448 KiB if it fits, else alias d_out (pipeline-safe: consumer
    // reads slot t+2 strictly before overwriting slot t).
    float* h0;
    const size_t need = 458752 + 67108864;
    if (ws_size >= need) h0 = (float*)(ws + 458752);
    else                 h0 = out;

    prep_frags<<<48, 512, 0, stream>>>(W0, U0, W1, U1, frags, flags);
    gru_pipe<<<32, 512, 0, stream>>>(x, frags, b0, b1, h0, out, flags);
}

// Round 6
// 709.258 us; speedup vs baseline: 2.2038x; 1.1933x over previous
//
#include <hip/hip_runtime.h>
#include <cstdint>
#include <cstddef>

typedef __bf16 bf16x8 __attribute__((ext_vector_type(8)));
typedef __bf16 bf16x4 __attribute__((ext_vector_type(4)));
typedef float  f32x4  __attribute__((ext_vector_type(4)));

#define MFMA16(a,b,c) __builtin_amdgcn_mfma_f32_16x16x32_bf16((a),(b),(c),0,0,0)

// LDS-only barrier: the per-step double-buffer handoff needs lgkmcnt(0) only.
// Global stores are drained explicitly at publish points (BAR_FULL).
#define BAR_LGKM() __asm__ volatile("s_waitcnt lgkmcnt(0)\n\ts_barrier" ::: "memory")
#define BAR_FULL() __asm__ volatile("s_waitcnt vmcnt(0) lgkmcnt(0)\n\ts_barrier" ::: "memory")

// Problem: B=256, T=512, D=H=128, 3H=384. x/out batch stride = 65536 elems.
// One 32-block kernel: blocks 0..15 = layer 0 (producer), 16..31 = layer 1
// (consumer, lagged 4..7 steps). h0 crosses XCDs via nt stores/loads (bypass
// non-coherent L2s) + per-pair agent-scope progress flags (64B-padded).

// ---------------------------------------------------------------------------
// prep_frags: stacked-weight B-frags, K=256 ([W(128) ; U(128)]), + flag init.
// Frag layout (16x16x32): B[k][n], n = lane&15, k = kt*32 + (lane>>4)*8 + j.
// Elem offset = ((ct*8+kt)*64 + lane)*8 + j, ct 0..23 (z:0-7,r:8-15,h:16-23),
// kt 0..7 (kt<4 -> W rows k, kt>=4 -> U rows k-128). Per layer: 98304 bf16.
// ---------------------------------------------------------------------------
__global__ void prep_frags(const float* __restrict__ W0, const float* __restrict__ U0,
                           const float* __restrict__ W1, const float* __restrict__ U1,
                           __bf16* __restrict__ frags, int* __restrict__ flags)
{
    if (blockIdx.x == 0 && threadIdx.x < 16) flags[threadIdx.x * 16] = 0;
    int id = blockIdx.x * 512 + threadIdx.x;      // 0..24575
    int layer = id / 12288;
    int r     = id % 12288;                       // (ct*8+kt)*64 + lane
    int lane = r & 63;
    int ctkt = r >> 6;                            // 0..191
    int kt = ctkt & 7;
    int ct = ctkt >> 3;
    const float* Wsrc = layer ? W1 : W0;
    const float* Usrc = layer ? U1 : U0;
    int n  = ct * 16 + (lane & 15);
    int k0 = kt * 32 + (lane >> 4) * 8;           // never straddles 128
    const float* src = (k0 < 128) ? (Wsrc + (size_t)k0 * 384)
                                  : (Usrc + (size_t)(k0 - 128) * 384);
    __bf16* dst = frags + (size_t)layer * 98304 + (size_t)r * 8;
#pragma unroll
    for (int j = 0; j < 8; j++)
        dst[j] = (__bf16)src[(size_t)j * 384 + n];
}

// ---------------------------------------------------------------------------
// gru_pipe: both GRU layers, pipelined across block pairs.
// Per block: 16 batch rows, 512 threads (8 waves, 2/SIMD). Wave w owns hidden
// col j=16w+l15 for all gates. A=[x_t | h_{t-1}] bf16 K=256, LDS stride 264,
// double-buffered, ONE lgkm-only barrier/step. acc: z(K256), r(K256),
// xh(kt0-3), rec_h(kt4-7) — reset_after multiplies r into recurrent only.
// Producer publishes flag=t every 4th step (t%4==3) after a FULL drain
// barrier: flag F asserts h0 steps 0..F-1 are in HBM (nt stores drained).
// Youngest outstanding store at a publish is ~1 full step old -> drain ~free.
// h0 may alias out (small-ws fallback): consumer reads slot t+2 strictly
// before overwriting slot t. No __restrict__ on x/h0/out.
// ---------------------------------------------------------------------------
__global__ __launch_bounds__(512, 2) void gru_pipe(
    const float* x, const __bf16* __restrict__ frags,
    const float* __restrict__ b0, const float* __restrict__ b1,
    float* h0, float* out, int* flags)
{
    __shared__ __align__(16) __bf16 ab[2][16 * 264];

    const int tid = threadIdx.x;
    const int wave = tid >> 6, lane = tid & 63;
    const int l15 = lane & 15, quad = lane >> 4;
    const int pair  = blockIdx.x & 15;
    const int layer = blockIdx.x >> 4;
    const int B0 = pair * 16;
    int* const flagp = flags + pair * 16;          // one 64B line per pair

    const __bf16* Bf  = frags + (size_t)layer * 98304;
    const float* bias = layer ? b1 : b0;
    const float* xin  = layer ? h0 : x;
    float*       hout = layer ? out : h0;

    // persistent stacked B-frags: 3 gates x 8 kt = 24 frags
    bf16x8 bfr[3][8];
#pragma unroll
    for (int g = 0; g < 3; g++) {
        int ct = 8 * g + wave;
#pragma unroll
        for (int kt = 0; kt < 8; kt++)
            bfr[g][kt] = *(const bf16x8*)(Bf + (size_t)((ct * 8 + kt) * 64 + lane) * 8);
    }

    const int j = wave * 16 + l15;
    const float bz  = bias[j]       + bias[384 + j];
    const float br  = bias[128 + j] + bias[512 + j];
    const float bih = bias[256 + j];
    const float brh = bias[640 + j];

    // staging map: 512 threads cover 16 rows x 128 cols (4 floats each)
    const int srow = tid >> 5;
    const int c4   = (tid & 31) * 4;
    const float* px = xin + (size_t)(B0 + srow) * 65536 + c4;
    const int sidx = srow * 264 + c4;

    const size_t obase = (size_t)(B0 + quad * 4) * 65536 + j;

    int known = 0;
    if (layer) {
        while (known < 2) {
            __builtin_amdgcn_s_sleep(4);
            known = __hip_atomic_load(flagp, __ATOMIC_RELAXED,
                                      __HIP_MEMORY_SCOPE_AGENT);
        }
    }

    // ---- prologue: stage step-0 input, zero h-part, preload step 1 ----
    f32x4 vc = layer ? __builtin_nontemporal_load((const f32x4*)px)
                     : *(const f32x4*)px;
    {
        bf16x4 hv;
        hv.x = (__bf16)vc[0]; hv.y = (__bf16)vc[1];
        hv.z = (__bf16)vc[2]; hv.w = (__bf16)vc[3];
        *(bf16x4*)&ab[0][sidx] = hv;
    }
    if (tid < 256) {
        int row = tid >> 4, seg = tid & 15;
        *(uint4*)&ab[0][row * 264 + 128 + seg * 8] = make_uint4(0, 0, 0, 0);
    }
    __syncthreads();
    vc = layer ? __builtin_nontemporal_load((const f32x4*)(px + 128))
               : *(const f32x4*)(px + 128);

    float hold[4] = {0.f, 0.f, 0.f, 0.f};
    const int abase = l15 * 264 + quad * 8;

    for (int t = 0; t < 512; t++) {
        const int cur = t & 1, nxt = cur ^ 1;

        if (layer) {                                // gate the t+2 prefetch
            int need = t + 3; if (need > 512) need = 512;
            while (known < need) {
                __builtin_amdgcn_s_sleep(4);
                known = __hip_atomic_load(flagp, __ATOMIC_RELAXED,
                                          __HIP_MEMORY_SCOPE_AGENT);
            }
        }
        const int t2 = (t < 510) ? (t + 2) : 511;
        f32x4 vn = layer
            ? __builtin_nontemporal_load((const f32x4*)(px + (size_t)t2 * 128))
            : *(const f32x4*)(px + (size_t)t2 * 128);

        // A-frags: 8 K-slabs (x: kt 0..3, h: kt 4..7)
        bf16x8 A[8];
#pragma unroll
        for (int kt = 0; kt < 8; kt++)
            A[kt] = *(const bf16x8*)&ab[cur][abase + kt * 32];

        f32x4 acc[4] = {{0,0,0,0},{0,0,0,0},{0,0,0,0},{0,0,0,0}};
#pragma unroll
        for (int kt = 0; kt < 8; kt++) {
            acc[0] = MFMA16(A[kt], bfr[0][kt], acc[0]);          // z (merged)
            acc[1] = MFMA16(A[kt], bfr[1][kt], acc[1]);          // r (merged)
            acc[(kt < 4) ? 2 : 3] = MFMA16(A[kt], bfr[2][kt], acc[(kt < 4) ? 2 : 3]);
        }

        float hnew[4];
#pragma unroll
        for (int r = 0; r < 4; r++) {
            float zp = acc[0][r] + bz;
            float rp = acc[1][r] + br;
            float z  = __builtin_amdgcn_rcpf(1.f + __expf(-zp));
            float rg = __builtin_amdgcn_rcpf(1.f + __expf(-rp));
            float hp = (acc[2][r] + bih) + rg * (acc[3][r] + brh);
            float e2 = __expf(2.f * hp);
            float th = 1.f - 2.f * __builtin_amdgcn_rcpf(e2 + 1.f);
            hnew[r] = th + z * (hold[r] - th);
            hold[r] = hnew[r];
        }

        // stage step t+1 input (vc from previous prefetch)
        {
            bf16x4 hv;
            hv.x = (__bf16)vc[0]; hv.y = (__bf16)vc[1];
            hv.z = (__bf16)vc[2]; hv.w = (__bf16)vc[3];
            *(bf16x4*)&ab[nxt][sidx] = hv;
        }
        // h_t -> LDS h-part (cols 128..255)
#pragma unroll
        for (int r = 0; r < 4; r++)
            ab[nxt][(quad * 4 + r) * 264 + 128 + j] = (__bf16)hnew[r];

        // barrier: lgkm-only normally; full drain + publish every 4th step
        if (layer == 0 && (t & 3) == 3) {
            BAR_FULL();                 // h0 stores of steps <= t-1 in HBM
            if (tid == 0)
                __hip_atomic_store(flagp, t, __ATOMIC_RELAXED,
                                   __HIP_MEMORY_SCOPE_AGENT);
        } else {
            BAR_LGKM();
        }

        // h_t -> global (drains during subsequent steps)
        if (layer == 0) {
#pragma unroll
            for (int r = 0; r < 4; r++)
                __builtin_nontemporal_store(hnew[r],
                    hout + obase + (size_t)r * 65536 + (size_t)t * 128);
        } else {
#pragma unroll
            for (int r = 0; r < 4; r++)
                hout[obase + (size_t)r * 65536 + (size_t)t * 128] = hnew[r];
        }

        vc = vn;
    }

    if (layer == 0) {
        BAR_FULL();        // drain final h0 stores (incl. step 511)
        if (tid == 0)
            __hip_atomic_store(flagp, 512, __ATOMIC_RELAXED,
                               __HIP_MEMORY_SCOPE_AGENT);
    }
}

// ---------------------------------------------------------------------------
extern "C" void kernel_launch(void* const* d_in, const int* in_sizes, int n_in,
                              void* d_out, int out_size, void* d_ws, size_t ws_size,
                              hipStream_t stream)
{
    const float* x  = (const float*)d_in[0];
    const float* W0 = (const float*)d_in[1];
    const float* U0 = (const float*)d_in[2];
    const float* b0 = (const float*)d_in[3];
    const float* W1 = (const float*)d_in[4];
    const float* U1 = (const float*)d_in[5];
    const float* b1 = (const float*)d_in[6];
    float* out = (float*)d_out;

    char* ws = (char*)d_ws;
    __bf16* frags = (__bf16*)ws;                 // 2 * 98304 bf16 = 393,216 B
    int*    flags = (int*)(ws + 393216);         // 16 pairs x 64 B = 1024 B
    // h0 at ws + 448 KiB if it fits, else alias d_out (pipeline-safe: consumer
    // reads slot t+2 strictly before overwriting slot t).
    float* h0;
    const size_t need = 458752 + 67108864;
    if (ws_size >= need) h0 = (float*)(ws + 458752);
    else                 h0 = out;

    prep_frags<<<48, 512, 0, stream>>>(W0, U0, W1, U1, frags, flags);
    gru_pipe<<<32, 512, 0, stream>>>(x, frags, b0, b1, h0, out, flags);
}